// Round 18
// baseline (189.063 us; speedup 1.0000x reference)
//
#include <hip/hip_runtime.h>
#include <math.h>

#define HEADS 8
#define DK 32
#define B_ 4
#define C_ 256
#define NVOX 1728   // 12*12*12
#define XPITCH 136  // fproj x-chunk LDS pitch (shorts)
#define CPITCH 36   // fproj cbuf pitch (floats)
#define LOG2E 1.44269504088896f
#define JSPLIT 3    // j-dimension split (27 = 3*9 tiles)
#define NJT 9       // j-tiles per block
#define ITILES 14   // ceil(1728/128) i-tiles (tail masked)

typedef _Float16 f16x8 __attribute__((ext_vector_type(8)));
typedef __fp16 fp16x2 __attribute__((ext_vector_type(2)));
typedef float f32x16 __attribute__((ext_vector_type(16)));

__device__ inline float h2f(short s) {
    _Float16 h = *(_Float16*)&s;
    return (float)h;
}
__device__ inline f32x16 mfma32h(f16x8 a, f16x8 b, f32x16 c) {
    return __builtin_amdgcn_mfma_f32_32x32x16_f16(a, b, c, 0, 0, 0);
}
// async global->LDS DMA, 16B per lane; LDS dest = wave-uniform base + lane*16
__device__ __forceinline__ void gl_lds16(const short* g, short* l) {
    __builtin_amdgcn_global_load_lds(
        (const __attribute__((address_space(1))) unsigned int*)g,
        (__attribute__((address_space(3))) unsigned int*)l, 16, 0, 0);
}

union H8 { _Float16 h[8]; uint4 v; f16x8 f; };
union PW { fp16x2 h2; unsigned int u; };

// ---------------------------------------------------------------------------
// Fused prep (weight section deleted — fproj cvt's fp32 weights at preload):
//   [0,432) x transpose->f16 | [432,648) pos per-h (batch-independent, R16)
// ---------------------------------------------------------------------------
__global__ __launch_bounds__(256)
void prep_kernel(const float* __restrict__ x,
                 const float* __restrict__ rel_d, const float* __restrict__ rel_h,
                 const float* __restrict__ rel_w,
                 short* __restrict__ xf, short* __restrict__ posf) {
    __shared__ float tile[64][65];
    int bid = blockIdx.x;
    int t = threadIdx.x;

    if (bid < 432) {                       // ---- x[b][c][n] -> xf[b][n][c] ----
        int q = bid;                       // 432 blocks: (27, 4, 4)
        int nb = (q % 27) * 64;
        int c0 = ((q / 27) % 4) * 64;
        int b  = q / 108;
        const float* xb = x + (size_t)b * C_ * NVOX;
        for (int e = t; e < 1024; e += 256) {
            int ci = e >> 4, n4 = (e & 15) * 4;
            float4 v = *(const float4*)&xb[(size_t)(c0 + ci) * NVOX + nb + n4];
            tile[ci][n4 + 0] = v.x;
            tile[ci][n4 + 1] = v.y;
            tile[ci][n4 + 2] = v.z;
            tile[ci][n4 + 3] = v.w;
        }
        __syncthreads();
        for (int e = t; e < 512; e += 256) {
            int n = e >> 3, cg = (e & 7) * 8;
            H8 hi;
            #pragma unroll
            for (int j = 0; j < 8; j++) hi.h[j] = (_Float16)tile[cg + j][n];
            *(uint4*)&xf[((size_t)b * NVOX + nb + n) * C_ + c0 + cg] = hi.v;
        }
    } else {                               // ---- pos -> posf[h][n][32] ----
        int q = bid - 432;                 // 216 blocks: (27, 8)
        int nb = (q % 27) * 64;
        int h  = q / 27;
        int nl = t & 63, dd0 = (t >> 6) * 8;
        int n = nb + nl;
        int di = n / 144, wi = (n / 12) % 12, hi = n % 12;
        H8 ph;
        #pragma unroll
        for (int o = 0; o < 8; o++) {
            int hd = h * DK + dd0 + o;
            ph.h[o] = (_Float16)(rel_d[hd * 12 + di] + rel_w[hd * 12 + wi] +
                                 rel_h[hd * 12 + hi]);
        }
        *(uint4*)&posf[((size_t)h * NVOX + n) * DK + dd0] = ph.v;
    }
}

// ---------------------------------------------------------------------------
// MFMA projection: A-frags preloaded from fp32 weights with STATIC indices
// (R17's `wreg[ch*8+ks]` under `#pragma unroll 1` was runtime-indexed ->
// rule #20 scratch spill: VGPR_Count 28, WRITE 93 MB, 67 us.  Fixed by
// explicit two-chunk unroll — R12's proven-compiling pattern.)
// grid (27, HEADS, B_), block 384.
// ---------------------------------------------------------------------------
struct FS {
    union {
        short xs[64 * XPITCH];
        float cbuf[3][64][CPITCH];
    } u;
};

__global__ __launch_bounds__(384, 4)
void fproj_kernel(const short* __restrict__ xf,
                  const float* __restrict__ wq, const float* __restrict__ wk,
                  const float* __restrict__ wv,
                  const float* __restrict__ bq, const float* __restrict__ bk,
                  const float* __restrict__ bv,
                  short* __restrict__ Qf, short* __restrict__ Kf,
                  short* __restrict__ Vf) {
    __shared__ FS sm;
    int nb = blockIdx.x * 64, h = blockIdx.y, b = blockIdx.z;
    int bh = b * HEADS + h;
    int t = threadIdx.x;
    int w = t >> 6, l = t & 63, ln = l & 31, hv = l >> 5;
    int mat = w >> 1, nh = w & 1;

    const short* xb = xf + ((size_t)b * NVOX + nb) * C_;
    const float* wsrc = (mat == 0) ? wq : (mat == 1) ? wk : wv;
    const float* wA = wsrc + (size_t)(h * DK + ln) * C_;   // lane's fp32 w row
    int xrow = (nh * 32 + ln) * XPITCH;

    // ---- preload all 16 A-fragments (fp32 -> f16), STATIC indices ----
    f16x8 wreg[16];
    #pragma unroll
    for (int q = 0; q < 16; q++) {
        float4 w0 = *(const float4*)&wA[q * 16 + hv * 8];
        float4 w1 = *(const float4*)&wA[q * 16 + hv * 8 + 4];
        H8 ah;
        ah.h[0] = (_Float16)w0.x; ah.h[1] = (_Float16)w0.y;
        ah.h[2] = (_Float16)w0.z; ah.h[3] = (_Float16)w0.w;
        ah.h[4] = (_Float16)w1.x; ah.h[5] = (_Float16)w1.y;
        ah.h[6] = (_Float16)w1.z; ah.h[7] = (_Float16)w1.w;
        wreg[q] = ah.f;
    }

    f32x16 acc;
    #pragma unroll
    for (int r = 0; r < 16; r++) acc[r] = 0.f;

    // ---- chunk 0: stage -> MFMA (wreg[0..7], static) ----
    for (int e = t; e < 1024; e += 384) {
        int row = e >> 4, c8 = (e & 15) * 8;
        *(uint4*)&sm.u.xs[row * XPITCH + c8] =
            *(const uint4*)&xb[row * C_ + c8];
    }
    __syncthreads();
    #pragma unroll
    for (int ks = 0; ks < 8; ks++) {
        f16x8 bfr = *(const f16x8*)&sm.u.xs[xrow + ks * 16 + hv * 8];
        acc = mfma32h(wreg[ks], bfr, acc);
    }
    __syncthreads();

    // ---- chunk 1: stage -> MFMA (wreg[8..15], static) ----
    for (int e = t; e < 1024; e += 384) {
        int row = e >> 4, c8 = (e & 15) * 8;
        *(uint4*)&sm.u.xs[row * XPITCH + c8] =
            *(const uint4*)&xb[row * C_ + 128 + c8];
    }
    __syncthreads();
    #pragma unroll
    for (int ks = 0; ks < 8; ks++) {
        f16x8 bfr = *(const f16x8*)&sm.u.xs[xrow + ks * 16 + hv * 8];
        acc = mfma32h(wreg[8 + ks], bfr, acc);
    }
    __syncthreads();   // x tile dead; reuse as cbuf

    const float* bias = (mat == 0) ? bq : (mat == 1) ? bk : bv;
    int ncol = nh * 32 + ln;
    #pragma unroll
    for (int q2 = 0; q2 < 4; q2++) {
        float4 cv;
        float* cvp = (float*)&cv;
        #pragma unroll
        for (int m = 0; m < 4; m++) {
            int o_loc = 8 * q2 + 4 * hv + m;
            cvp[m] = acc[4 * q2 + m] + bias[h * DK + o_loc];
        }
        *(float4*)&sm.u.cbuf[mat][ncol][8 * q2 + 4 * hv] = cv;
    }
    __syncthreads();

    if (t < 256) {                          // ---- readout q/k (32-wide) ----
        int n = t >> 2, ddg = (t & 3) * 8;
        H8 qh, kh;
        #pragma unroll
        for (int j = 0; j < 8; j++) {
            qh.h[j] = (_Float16)sm.u.cbuf[0][n][ddg + j];
            kh.h[j] = (_Float16)sm.u.cbuf[1][n][ddg + j];
        }
        *(uint4*)&Qf[((size_t)bh * NVOX + nb + n) * DK + ddg] = qh.v;
        *(uint4*)&Kf[((size_t)bh * NVOX + nb + n) * DK + ddg] = kh.v;
    }
    if (t < 256) {                          // ---- readout v ----
        int d = t >> 3, ng = (t & 7) * 8;
        H8 vv;
        #pragma unroll
        for (int j = 0; j < 8; j++)
            vv.h[j] = (_Float16)sm.u.cbuf[2][ng + j][d];
        *(uint4*)&Vf[((size_t)bh * DK + d) * NVOX + nb + ng] = vv.v;
    }
}

// ---------------------------------------------------------------------------
// Flash attention partial (R16-EXACT — best measured attn, 54.4 us):
//  - 4 waves/block, i-tile 128; fragment-major XOR-swizzled LDS (0 conflicts)
//  - global_load_lds staging, double-buffered, 1 barrier/iter
//  - Q'=[q;pos] from 32-wide Qf + shared per-h posf (pos dedup, R16)
//  - P in-register (cvt_pkrtz+permlane32_swap); defer-max (THR=4, log2)
//  - T1 bijective XCD swizzle; T5 setprio; launch_bounds(256,4)
//  grid 1344 = 8 XCD x 168, block 256.
// ---------------------------------------------------------------------------
__global__ __launch_bounds__(256, 4)
void attn_kernel(const short* __restrict__ Qf, const short* __restrict__ Kf,
                 const short* __restrict__ Vf, const short* __restrict__ posf,
                 short* __restrict__ wsO, float* __restrict__ wsM,
                 float* __restrict__ wsL) {
    __shared__ __align__(16) short Ksm[2][4096];
    __shared__ __align__(16) short Vsm[2][2048];
    // ---- XCD-clustering decode: id = x8 + 8*(k + 42*g), bh = 8g + x8 ----
    int id = blockIdx.x;
    int x8 = id & 7;
    int rr = id >> 3;            // 0..167
    int g  = rr / 42;            // 0..3
    int k_ = rr - g * 42;        // 0..41
    int bh = g * 8 + x8;
    int it = k_ / 3;
    int jp = k_ - it * 3;
    int t = threadIdx.x;
    int w  = t >> 6;       // wave 0..3
    int l  = t & 63;
    int ln = l & 31;
    int hv = l >> 5;
    int i_glob = it * 128 + w * 32 + ln;
    int iq = i_glob < NVOX ? i_glob : NVOX - 1;

    const short* Qp = Qf + (size_t)bh * NVOX * DK;       // 32-wide q
    const short* Kp = Kf + (size_t)bh * NVOX * DK;
    const short* Vp = Vf + (size_t)bh * DK * NVOX;
    const short* Pp = posf + (size_t)(bh & 7) * NVOX * DK;  // per-h pos

    f16x8 qf[4];
    #pragma unroll
    for (int ks = 0; ks < 2; ks++)       // Q' cols 0-31 = q
        qf[ks] = *(const f16x8*)&Qp[(size_t)iq * DK + ks * 16 + hv * 8];
    #pragma unroll
    for (int ks = 2; ks < 4; ks++)       // Q' cols 32-63 = pos (shared)
        qf[ks] = *(const f16x8*)&Pp[(size_t)iq * DK + (ks - 2) * 16 + hv * 8];

    int jb0 = jp * NJT * 64;

    // staging: wave w owns K'-chunks {w, w+4} and V-region w (vb = 2w+hv)
    // K' = [k; q]: chunks 0-3 from Kf, chunks 4-7 from Qf (q part)
    const short* gk0 = Kp + (size_t)(jb0 + (l ^ (w + 0))) * DK + (w + 0) * 8;
    const short* gk1 = Qp + (size_t)(jb0 + (l ^ (w + 4))) * DK + (w + 0) * 8;
    int vb0 = 2 * w + hv;
    const short* gv0 = Vp + (size_t)(ln ^ vb0) * NVOX + jb0 + vb0 * 8;

#define STAGE(bufp) do {                                   \
        short* kl_ = &Ksm[bufp][0];                        \
        short* vl_ = &Vsm[bufp][0];                        \
        gl_lds16(gk0, kl_ + (w + 0) * 512);                \
        gl_lds16(gk1, kl_ + (w + 4) * 512);                \
        gl_lds16(gv0, vl_ + (w + 0) * 512);                \
        gk0 += 64 * DK; gk1 += 64 * DK; gv0 += 64;         \
    } while (0)

    float mL = -INFINITY;
    float lsum = 0.f;
    f32x16 O;
    #pragma unroll
    for (int r = 0; r < 16; r++) O[r] = 0.f;

    STAGE(0);

    #pragma unroll 1
    for (int jt = 0; jt < NJT; ++jt) {
        int buf = jt & 1;
        __syncthreads();
        if (jt + 1 < NJT) STAGE(buf ^ 1);

        const short* Kb = &Ksm[buf][0];
        const short* Vb = &Vsm[buf][0];

        f32x16 sc[2];
        __builtin_amdgcn_s_setprio(1);
        #pragma unroll
        for (int js = 0; js < 2; js++) {
            f32x16 s;
            #pragma unroll
            for (int r = 0; r < 16; r++) s[r] = 0.f;
            #pragma unroll
            for (int ks = 0; ks < 4; ks++) {
                int kb = ks * 2 + hv;
                f16x8 kfr = *(const f16x8*)&Kb[kb * 512 + js * 256 + (ln ^ kb) * 8];
                s = mfma32h(kfr, qf[ks], s);
            }
            sc[js] = s;
        }
        __builtin_amdgcn_s_setprio(0);

        float m0 = fmaxf(sc[0][0], sc[1][0]);
        float m1 = fmaxf(sc[0][1], sc[1][1]);
        float m2 = fmaxf(sc[0][2], sc[1][2]);
        float m3 = fmaxf(sc[0][3], sc[1][3]);
        #pragma unroll
        for (int r = 4; r < 16; r += 4) {
            m0 = fmaxf(m0, fmaxf(sc[0][r + 0], sc[1][r + 0]));
            m1 = fmaxf(m1, fmaxf(sc[0][r + 1], sc[1][r + 1]));
            m2 = fmaxf(m2, fmaxf(sc[0][r + 2], sc[1][r + 2]));
            m3 = fmaxf(m3, fmaxf(sc[0][r + 3], sc[1][r + 3]));
        }
        float mx = fmaxf(fmaxf(m0, m1), fmaxf(m2, m3));
        mx = fmaxf(mx, __shfl_xor(mx, 32));
        float mxl = mx * LOG2E;
        if (!__all(mxl <= mL + 4.0f)) {      // rescale only when max really grew
            float mLn = fmaxf(mL, mxl);
            float alpha = exp2f(mL - mLn);
            mL = mLn;
            lsum *= alpha;
            #pragma unroll
            for (int r = 0; r < 16; r++) O[r] *= alpha;
        }

        float ps0 = 0.f, ps1 = 0.f, ps2 = 0.f, ps3 = 0.f;
        #pragma unroll
        for (int js = 0; js < 2; js++) {
            #pragma unroll
            for (int r = 0; r < 16; r += 4) {
                float p0 = exp2f(fmaf(sc[js][r + 0], LOG2E, -mL));
                float p1 = exp2f(fmaf(sc[js][r + 1], LOG2E, -mL));
                float p2 = exp2f(fmaf(sc[js][r + 2], LOG2E, -mL));
                float p3 = exp2f(fmaf(sc[js][r + 3], LOG2E, -mL));
                sc[js][r + 0] = p0; sc[js][r + 1] = p1;
                sc[js][r + 2] = p2; sc[js][r + 3] = p3;
                ps0 += p0; ps1 += p1; ps2 += p2; ps3 += p3;
            }
        }
        float ps = (ps0 + ps1) + (ps2 + ps3);
        ps += __shfl_xor(ps, 32);
        lsum += ps;

        __builtin_amdgcn_s_setprio(1);
        #pragma unroll
        for (int ks = 0; ks < 4; ks++) {
            int js = ks >> 1, u8 = (ks & 1) * 8;
            PW a0p, a1p, b0p, b1p;
            a0p.h2 = __builtin_amdgcn_cvt_pkrtz(sc[js][u8 + 0], sc[js][u8 + 1]);
            a1p.h2 = __builtin_amdgcn_cvt_pkrtz(sc[js][u8 + 2], sc[js][u8 + 3]);
            b0p.h2 = __builtin_amdgcn_cvt_pkrtz(sc[js][u8 + 4], sc[js][u8 + 5]);
            b1p.h2 = __builtin_amdgcn_cvt_pkrtz(sc[js][u8 + 6], sc[js][u8 + 7]);
            auto r0 = __builtin_amdgcn_permlane32_swap(a0p.u, b0p.u, false, false);
            auto r1 = __builtin_amdgcn_permlane32_swap(a1p.u, b1p.u, false, false);
            union { unsigned int w4[4]; f16x8 f; } pb;
            pb.w4[0] = r0[0]; pb.w4[1] = r1[0];
            pb.w4[2] = r0[1]; pb.w4[3] = r1[1];
            int vb = ks * 2 + hv;
            f16x8 va = *(const f16x8*)&Vb[vb * 256 + (ln ^ vb) * 8];
            O = mfma32h(va, pb.f, O);
        }
        __builtin_amdgcn_s_setprio(0);
    }
#undef STAGE

    if (i_glob < NVOX) {
        short* Op = wsO + ((size_t)jp * (B_ * HEADS) + bh) * DK * NVOX;
        #pragma unroll
        for (int r = 0; r < 16; r++) {
            int d = (r & 3) + 8 * (r >> 2) + 4 * hv;
            _Float16 oh = (_Float16)O[r];
            Op[(size_t)d * NVOX + i_glob] = *(short*)&oh;
        }
        if (hv == 0) {
            size_t mo = ((size_t)jp * (B_ * HEADS) + bh) * NVOX + i_glob;
            wsM[mo] = mL;
            wsL[mo] = lsum;
        }
    }
}

// ---------------------------------------------------------------------------
// Combine the three j-third partials (flash merge identity), 4-wide vectorized.
// ---------------------------------------------------------------------------
__global__ void combine_kernel(const short* __restrict__ wsO,
                               const float* __restrict__ wsM,
                               const float* __restrict__ wsL,
                               float* __restrict__ out) {
    int idx = (blockIdx.x * 256 + threadIdx.x) * 4;   // 1,769,472 total
    int i = idx % NVOX;
    int bh = (idx / NVOX) >> 5;
    const size_t oh = (size_t)B_ * HEADS * DK * NVOX;
    const size_t mh = (size_t)B_ * HEADS * NVOX;
    size_t mo = (size_t)bh * NVOX + i;
    float4 m0 = *(const float4*)&wsM[mo];
    float4 m1 = *(const float4*)&wsM[mh + mo];
    float4 m2 = *(const float4*)&wsM[2 * mh + mo];
    float4 l0 = *(const float4*)&wsL[mo];
    float4 l1 = *(const float4*)&wsL[mh + mo];
    float4 l2 = *(const float4*)&wsL[2 * mh + mo];
    uint2 o0u = *(const uint2*)&wsO[idx];
    uint2 o1u = *(const uint2*)&wsO[oh + idx];
    uint2 o2u = *(const uint2*)&wsO[2 * oh + idx];
    const short* o0s = (const short*)&o0u;
    const short* o1s = (const short*)&o1u;
    const short* o2s = (const short*)&o2u;
    const float* m0p = (const float*)&m0; const float* m1p = (const float*)&m1;
    const float* m2p = (const float*)&m2;
    const float* l0p = (const float*)&l0; const float* l1p = (const float*)&l1;
    const float* l2p = (const float*)&l2;
    float4 res;
    float* rp = (float*)&res;
    #pragma unroll
    for (int j = 0; j < 4; j++) {
        float m = fmaxf(fmaxf(m0p[j], m1p[j]), m2p[j]);
        float a0 = exp2f(m0p[j] - m);
        float a1 = exp2f(m1p[j] - m);
        float a2 = exp2f(m2p[j] - m);
        rp[j] = (a0 * h2f(o0s[j]) + a1 * h2f(o1s[j]) + a2 * h2f(o2s[j])) /
                (a0 * l0p[j] + a1 * l1p[j] + a2 * l2p[j]);
    }
    *(float4*)&out[idx] = res;
}

// ---------------------------------------------------------------------------
extern "C" void kernel_launch(void* const* d_in, const int* in_sizes, int n_in,
                              void* d_out, int out_size, void* d_ws, size_t ws_size,
                              hipStream_t stream) {
    const float* x     = (const float*)d_in[0];
    const float* wq    = (const float*)d_in[1];
    const float* bq    = (const float*)d_in[2];
    const float* wk    = (const float*)d_in[3];
    const float* bk    = (const float*)d_in[4];
    const float* wv    = (const float*)d_in[5];
    const float* bv    = (const float*)d_in[6];
    const float* rel_d = (const float*)d_in[7];
    const float* rel_h = (const float*)d_in[8];
    const float* rel_w = (const float*)d_in[9];
    float* out = (float*)d_out;

    size_t vsz  = (size_t)B_ * HEADS * DK * NVOX;        // 1,769,472
    size_t psz  = (size_t)HEADS * NVOX * DK;             // 442,368
    short* Qf   = (short*)d_ws;                          // 32-wide
    short* Kf   = Qf + vsz;
    short* Vf   = Kf + vsz;
    short* posf = Vf + vsz;                              // per-h pos
    short* wsO  = posf + psz;                            // 3*vsz shorts (f16)
    float* wsM  = (float*)(wsO + 3 * vsz);               // 3*B*H*NVOX floats
    float* wsL  = wsM + 3 * (size_t)B_ * HEADS * NVOX;
    short* xf   = wsO;                                   // aliases wsO (dead before attn)

    prep_kernel<<<dim3(648), dim3(256), 0, stream>>>(
        x, rel_d, rel_h, rel_w, xf, posf);
    fproj_kernel<<<dim3(NVOX / 64, HEADS, B_), dim3(384), 0, stream>>>(
        xf, wq, wk, wv, bq, bk, bv, Qf, Kf, Vf);
    attn_kernel<<<dim3(ITILES * JSPLIT * HEADS * B_), dim3(256), 0, stream>>>(
        Qf, Kf, Vf, posf, wsO, wsM, wsL);
    combine_kernel<<<dim3((int)(vsz / 1024)), dim3(256), 0, stream>>>(wsO, wsM, wsL, out);
}

// Round 20
// 150.082 us; speedup vs baseline: 1.2597x; 1.2597x over previous
//
#include <hip/hip_runtime.h>
#include <math.h>

#define HEADS 8
#define DK 32
#define B_ 4
#define C_ 256
#define NVOX 1728   // 12*12*12
#define XPITCH 128  // fproj x-chunk LDS pitch (shorts); XOR-swizzled slots
#define CPITCH 36   // fproj cbuf pitch (floats)
#define LOG2E 1.44269504088896f
#define JSPLIT 3    // j-dimension split (27 = 3*9 tiles)
#define NJT 9       // j-tiles per block
#define ITILES 14   // ceil(1728/128) i-tiles (tail masked)

typedef _Float16 f16x8 __attribute__((ext_vector_type(8)));
typedef __fp16 fp16x2 __attribute__((ext_vector_type(2)));
typedef float f32x16 __attribute__((ext_vector_type(16)));

__device__ inline float h2f(short s) {
    _Float16 h = *(_Float16*)&s;
    return (float)h;
}
__device__ inline f32x16 mfma32h(f16x8 a, f16x8 b, f32x16 c) {
    return __builtin_amdgcn_mfma_f32_32x32x16_f16(a, b, c, 0, 0, 0);
}
// async global->LDS DMA, 16B per lane; LDS dest = wave-uniform base + lane*16
__device__ __forceinline__ void gl_lds16(const short* g, short* l) {
    __builtin_amdgcn_global_load_lds(
        (const __attribute__((address_space(1))) unsigned int*)g,
        (__attribute__((address_space(3))) unsigned int*)l, 16, 0, 0);
}

union H8 { _Float16 h[8]; uint4 v; };
union H4 { _Float16 h[4]; uint2 v; };
union PW { fp16x2 h2; unsigned int u; };

// ---------------------------------------------------------------------------
// Fused prep (R16-proven): [0,192) w->f16 | [192,624) x transpose (float4) |
// [624,840) pos per-h (batch-independent).
// (fp32-weight preload in fproj failed twice: R17 rule#20 runtime-index
//  spill, R18 union-built array still spilled — wf round-trip is cheaper.)
// ---------------------------------------------------------------------------
__global__ __launch_bounds__(256)
void prep_kernel(const float* __restrict__ x,
                 const float* __restrict__ wq, const float* __restrict__ wk,
                 const float* __restrict__ wv,
                 const float* __restrict__ rel_d, const float* __restrict__ rel_h,
                 const float* __restrict__ rel_w,
                 short* __restrict__ wf, short* __restrict__ xf,
                 short* __restrict__ posf) {
    __shared__ float tile[64][65];
    int bid = blockIdx.x;
    int t = threadIdx.x;

    if (bid < 192) {                       // ---- weights -> f16 (x4) ----
        int idx = (bid * 256 + t) * 4;     // 3*65536 total
        int m = idx >> 16;
        const float* w = (m == 0) ? wq : (m == 1) ? wk : wv;
        float4 v = *(const float4*)&w[idx & 65535];
        H4 hh;
        hh.h[0] = (_Float16)v.x; hh.h[1] = (_Float16)v.y;
        hh.h[2] = (_Float16)v.z; hh.h[3] = (_Float16)v.w;
        *(uint2*)&wf[idx] = hh.v;
    } else if (bid < 624) {                // ---- x[b][c][n] -> xf[b][n][c] ----
        int q = bid - 192;                 // 432 blocks: (27, 4, 4)
        int nb = (q % 27) * 64;
        int c0 = ((q / 27) % 4) * 64;
        int b  = q / 108;
        const float* xb = x + (size_t)b * C_ * NVOX;
        for (int e = t; e < 1024; e += 256) {
            int ci = e >> 4, n4 = (e & 15) * 4;
            float4 v = *(const float4*)&xb[(size_t)(c0 + ci) * NVOX + nb + n4];
            tile[ci][n4 + 0] = v.x;
            tile[ci][n4 + 1] = v.y;
            tile[ci][n4 + 2] = v.z;
            tile[ci][n4 + 3] = v.w;
        }
        __syncthreads();
        for (int e = t; e < 512; e += 256) {
            int n = e >> 3, cg = (e & 7) * 8;
            H8 hi;
            #pragma unroll
            for (int j = 0; j < 8; j++) hi.h[j] = (_Float16)tile[cg + j][n];
            *(uint4*)&xf[((size_t)b * NVOX + nb + n) * C_ + c0 + cg] = hi.v;
        }
    } else {                               // ---- pos -> posf[h][n][32] ----
        int q = bid - 624;                 // 216 blocks: (27, 8)
        int nb = (q % 27) * 64;
        int h  = q / 27;
        int nl = t & 63, dd0 = (t >> 6) * 8;
        int n = nb + nl;
        int di = n / 144, wi = (n / 12) % 12, hi = n % 12;
        H8 ph;
        #pragma unroll
        for (int o = 0; o < 8; o++) {
            int hd = h * DK + dd0 + o;
            ph.h[o] = (_Float16)(rel_d[hd * 12 + di] + rel_w[hd * 12 + wi] +
                                 rel_h[hd * 12 + hi]);
        }
        *(uint4*)&posf[((size_t)h * NVOX + n) * DK + dd0] = ph.v;
    }
}

// ---------------------------------------------------------------------------
// MFMA projection (R16 loop + XOR-swizzled xs: R17/R18 counters exposed
// 3.87M LDS bank-conflict cycles — XPITCH 136 rows stride 68 dwords,
// gcd(68,32)=4 -> 4-way conflict on every B-frag ds_read_b128.  Fix:
// XPITCH 128 (aligned) with slot ^= row&15 on BOTH write and read (same
// involution, rule 21): lanes sharing a slot class are (ln, ln+16) ->
// 2-way -> free per m136.)  grid (27, HEADS, B_), block 384.
// ---------------------------------------------------------------------------
struct FS {
    union {
        short xs[64 * XPITCH];             // 16384 B
        float cbuf[3][64][CPITCH];         // 27648 B
    } u;
};

__global__ __launch_bounds__(384, 4)
void fproj_kernel(const short* __restrict__ xf, const short* __restrict__ wf,
                  const float* __restrict__ bq, const float* __restrict__ bk,
                  const float* __restrict__ bv,
                  short* __restrict__ Qf, short* __restrict__ Kf,
                  short* __restrict__ Vf) {
    __shared__ FS sm;
    int nb = blockIdx.x * 64, h = blockIdx.y, b = blockIdx.z;
    int bh = b * HEADS + h;
    int t = threadIdx.x;
    int w = t >> 6, l = t & 63, ln = l & 31, hv = l >> 5;
    int mat = w >> 1, nh = w & 1;

    const short* xb = xf + ((size_t)b * NVOX + nb) * C_;
    const short* wA = wf + ((size_t)mat * C_ + h * DK + ln) * C_;
    int xrow = (nh * 32 + ln) * XPITCH;
    int rsw  = ln & 15;                    // read-side slot XOR

    f32x16 acc;
    #pragma unroll
    for (int r = 0; r < 16; r++) acc[r] = 0.f;

    #pragma unroll 1
    for (int ch = 0; ch < 2; ch++) {
        __syncthreads();
        for (int e = t; e < 1024; e += 384) {
            int row = e >> 4, slot = e & 15;
            *(uint4*)&sm.u.xs[row * XPITCH + ((slot ^ (row & 15)) * 8)] =
                *(const uint4*)&xb[row * C_ + ch * 128 + slot * 8];
        }
        __syncthreads();
        #pragma unroll 4
        for (int ks = 0; ks < 8; ks++) {
            int kl_ = ks * 16 + hv * 8;
            f16x8 a = *(const f16x8*)&wA[ch * 128 + kl_];
            f16x8 bfr = *(const f16x8*)
                &sm.u.xs[xrow + (((2 * ks + hv) ^ rsw) * 8)];
            acc = mfma32h(a, bfr, acc);
        }
    }
    __syncthreads();   // x tile dead; reuse as cbuf

    const float* bias = (mat == 0) ? bq : (mat == 1) ? bk : bv;
    int ncol = nh * 32 + ln;
    #pragma unroll
    for (int q2 = 0; q2 < 4; q2++) {
        float4 cv;
        float* cvp = (float*)&cv;
        #pragma unroll
        for (int m = 0; m < 4; m++) {
            int o_loc = 8 * q2 + 4 * hv + m;
            cvp[m] = acc[4 * q2 + m] + bias[h * DK + o_loc];
        }
        *(float4*)&sm.u.cbuf[mat][ncol][8 * q2 + 4 * hv] = cv;
    }
    __syncthreads();

    if (t < 256) {                          // ---- readout q/k (32-wide) ----
        int n = t >> 2, ddg = (t & 3) * 8;
        H8 qh, kh;
        #pragma unroll
        for (int j = 0; j < 8; j++) {
            qh.h[j] = (_Float16)sm.u.cbuf[0][n][ddg + j];
            kh.h[j] = (_Float16)sm.u.cbuf[1][n][ddg + j];
        }
        *(uint4*)&Qf[((size_t)bh * NVOX + nb + n) * DK + ddg] = qh.v;
        *(uint4*)&Kf[((size_t)bh * NVOX + nb + n) * DK + ddg] = kh.v;
    }
    if (t < 256) {                          // ---- readout v ----
        int d = t >> 3, ng = (t & 7) * 8;
        H8 vv;
        #pragma unroll
        for (int j = 0; j < 8; j++)
            vv.h[j] = (_Float16)sm.u.cbuf[2][ng + j][d];
        *(uint4*)&Vf[((size_t)bh * DK + d) * NVOX + nb + ng] = vv.v;
    }
}

// ---------------------------------------------------------------------------
// Flash attention partial (R16-EXACT — best measured attn, 54.4 us):
//  - 4 waves/block, i-tile 128; fragment-major XOR-swizzled LDS (0 conflicts)
//  - global_load_lds staging, double-buffered, 1 barrier/iter
//  - Q'=[q;pos] from 32-wide Qf + shared per-h posf (pos dedup, R16)
//  - P in-register (cvt_pkrtz+permlane32_swap); defer-max (THR=4, log2)
//  - T1 bijective XCD swizzle; T5 setprio; launch_bounds(256,4)
//  grid 1344 = 8 XCD x 168, block 256.
// ---------------------------------------------------------------------------
__global__ __launch_bounds__(256, 4)
void attn_kernel(const short* __restrict__ Qf, const short* __restrict__ Kf,
                 const short* __restrict__ Vf, const short* __restrict__ posf,
                 short* __restrict__ wsO, float* __restrict__ wsM,
                 float* __restrict__ wsL) {
    __shared__ __align__(16) short Ksm[2][4096];
    __shared__ __align__(16) short Vsm[2][2048];
    // ---- XCD-clustering decode: id = x8 + 8*(k + 42*g), bh = 8g + x8 ----
    int id = blockIdx.x;
    int x8 = id & 7;
    int rr = id >> 3;            // 0..167
    int g  = rr / 42;            // 0..3
    int k_ = rr - g * 42;        // 0..41
    int bh = g * 8 + x8;
    int it = k_ / 3;
    int jp = k_ - it * 3;
    int t = threadIdx.x;
    int w  = t >> 6;       // wave 0..3
    int l  = t & 63;
    int ln = l & 31;
    int hv = l >> 5;
    int i_glob = it * 128 + w * 32 + ln;
    int iq = i_glob < NVOX ? i_glob : NVOX - 1;

    const short* Qp = Qf + (size_t)bh * NVOX * DK;       // 32-wide q
    const short* Kp = Kf + (size_t)bh * NVOX * DK;
    const short* Vp = Vf + (size_t)bh * DK * NVOX;
    const short* Pp = posf + (size_t)(bh & 7) * NVOX * DK;  // per-h pos

    f16x8 qf[4];
    #pragma unroll
    for (int ks = 0; ks < 2; ks++)       // Q' cols 0-31 = q
        qf[ks] = *(const f16x8*)&Qp[(size_t)iq * DK + ks * 16 + hv * 8];
    #pragma unroll
    for (int ks = 2; ks < 4; ks++)       // Q' cols 32-63 = pos (shared)
        qf[ks] = *(const f16x8*)&Pp[(size_t)iq * DK + (ks - 2) * 16 + hv * 8];

    int jb0 = jp * NJT * 64;

    // staging: wave w owns K'-chunks {w, w+4} and V-region w (vb = 2w+hv)
    // K' = [k; q]: chunks 0-3 from Kf, chunks 4-7 from Qf (q part)
    const short* gk0 = Kp + (size_t)(jb0 + (l ^ (w + 0))) * DK + (w + 0) * 8;
    const short* gk1 = Qp + (size_t)(jb0 + (l ^ (w + 4))) * DK + (w + 0) * 8;
    int vb0 = 2 * w + hv;
    const short* gv0 = Vp + (size_t)(ln ^ vb0) * NVOX + jb0 + vb0 * 8;

#define STAGE(bufp) do {                                   \
        short* kl_ = &Ksm[bufp][0];                        \
        short* vl_ = &Vsm[bufp][0];                        \
        gl_lds16(gk0, kl_ + (w + 0) * 512);                \
        gl_lds16(gk1, kl_ + (w + 4) * 512);                \
        gl_lds16(gv0, vl_ + (w + 0) * 512);                \
        gk0 += 64 * DK; gk1 += 64 * DK; gv0 += 64;         \
    } while (0)

    float mL = -INFINITY;
    float lsum = 0.f;
    f32x16 O;
    #pragma unroll
    for (int r = 0; r < 16; r++) O[r] = 0.f;

    STAGE(0);

    #pragma unroll 1
    for (int jt = 0; jt < NJT; ++jt) {
        int buf = jt & 1;
        __syncthreads();
        if (jt + 1 < NJT) STAGE(buf ^ 1);

        const short* Kb = &Ksm[buf][0];
        const short* Vb = &Vsm[buf][0];

        f32x16 sc[2];
        __builtin_amdgcn_s_setprio(1);
        #pragma unroll
        for (int js = 0; js < 2; js++) {
            f32x16 s;
            #pragma unroll
            for (int r = 0; r < 16; r++) s[r] = 0.f;
            #pragma unroll
            for (int ks = 0; ks < 4; ks++) {
                int kb = ks * 2 + hv;
                f16x8 kfr = *(const f16x8*)&Kb[kb * 512 + js * 256 + (ln ^ kb) * 8];
                s = mfma32h(kfr, qf[ks], s);
            }
            sc[js] = s;
        }
        __builtin_amdgcn_s_setprio(0);

        float m0 = fmaxf(sc[0][0], sc[1][0]);
        float m1 = fmaxf(sc[0][1], sc[1][1]);
        float m2 = fmaxf(sc[0][2], sc[1][2]);
        float m3 = fmaxf(sc[0][3], sc[1][3]);
        #pragma unroll
        for (int r = 4; r < 16; r += 4) {
            m0 = fmaxf(m0, fmaxf(sc[0][r + 0], sc[1][r + 0]));
            m1 = fmaxf(m1, fmaxf(sc[0][r + 1], sc[1][r + 1]));
            m2 = fmaxf(m2, fmaxf(sc[0][r + 2], sc[1][r + 2]));
            m3 = fmaxf(m3, fmaxf(sc[0][r + 3], sc[1][r + 3]));
        }
        float mx = fmaxf(fmaxf(m0, m1), fmaxf(m2, m3));
        mx = fmaxf(mx, __shfl_xor(mx, 32));
        float mxl = mx * LOG2E;
        if (!__all(mxl <= mL + 4.0f)) {      // rescale only when max really grew
            float mLn = fmaxf(mL, mxl);
            float alpha = exp2f(mL - mLn);
            mL = mLn;
            lsum *= alpha;
            #pragma unroll
            for (int r = 0; r < 16; r++) O[r] *= alpha;
        }

        float ps0 = 0.f, ps1 = 0.f, ps2 = 0.f, ps3 = 0.f;
        #pragma unroll
        for (int js = 0; js < 2; js++) {
            #pragma unroll
            for (int r = 0; r < 16; r += 4) {
                float p0 = exp2f(fmaf(sc[js][r + 0], LOG2E, -mL));
                float p1 = exp2f(fmaf(sc[js][r + 1], LOG2E, -mL));
                float p2 = exp2f(fmaf(sc[js][r + 2], LOG2E, -mL));
                float p3 = exp2f(fmaf(sc[js][r + 3], LOG2E, -mL));
                sc[js][r + 0] = p0; sc[js][r + 1] = p1;
                sc[js][r + 2] = p2; sc[js][r + 3] = p3;
                ps0 += p0; ps1 += p1; ps2 += p2; ps3 += p3;
            }
        }
        float ps = (ps0 + ps1) + (ps2 + ps3);
        ps += __shfl_xor(ps, 32);
        lsum += ps;

        __builtin_amdgcn_s_setprio(1);
        #pragma unroll
        for (int ks = 0; ks < 4; ks++) {
            int js = ks >> 1, u8 = (ks & 1) * 8;
            PW a0p, a1p, b0p, b1p;
            a0p.h2 = __builtin_amdgcn_cvt_pkrtz(sc[js][u8 + 0], sc[js][u8 + 1]);
            a1p.h2 = __builtin_amdgcn_cvt_pkrtz(sc[js][u8 + 2], sc[js][u8 + 3]);
            b0p.h2 = __builtin_amdgcn_cvt_pkrtz(sc[js][u8 + 4], sc[js][u8 + 5]);
            b1p.h2 = __builtin_amdgcn_cvt_pkrtz(sc[js][u8 + 6], sc[js][u8 + 7]);
            auto r0 = __builtin_amdgcn_permlane32_swap(a0p.u, b0p.u, false, false);
            auto r1 = __builtin_amdgcn_permlane32_swap(a1p.u, b1p.u, false, false);
            union { unsigned int w4[4]; f16x8 f; } pb;
            pb.w4[0] = r0[0]; pb.w4[1] = r1[0];
            pb.w4[2] = r0[1]; pb.w4[3] = r1[1];
            int vb = ks * 2 + hv;
            f16x8 va = *(const f16x8*)&Vb[vb * 256 + (ln ^ vb) * 8];
            O = mfma32h(va, pb.f, O);
        }
        __builtin_amdgcn_s_setprio(0);
    }
#undef STAGE

    if (i_glob < NVOX) {
        short* Op = wsO + ((size_t)jp * (B_ * HEADS) + bh) * DK * NVOX;
        #pragma unroll
        for (int r = 0; r < 16; r++) {
            int d = (r & 3) + 8 * (r >> 2) + 4 * hv;
            _Float16 oh = (_Float16)O[r];
            Op[(size_t)d * NVOX + i_glob] = *(short*)&oh;
        }
        if (hv == 0) {
            size_t mo = ((size_t)jp * (B_ * HEADS) + bh) * NVOX + i_glob;
            wsM[mo] = mL;
            wsL[mo] = lsum;
        }
    }
}

// ---------------------------------------------------------------------------
// Combine the three j-third partials (flash merge identity), 4-wide vectorized.
// ---------------------------------------------------------------------------
__global__ void combine_kernel(const short* __restrict__ wsO,
                               const float* __restrict__ wsM,
                               const float* __restrict__ wsL,
                               float* __restrict__ out) {
    int idx = (blockIdx.x * 256 + threadIdx.x) * 4;   // 1,769,472 total
    int i = idx % NVOX;
    int bh = (idx / NVOX) >> 5;
    const size_t oh = (size_t)B_ * HEADS * DK * NVOX;
    const size_t mh = (size_t)B_ * HEADS * NVOX;
    size_t mo = (size_t)bh * NVOX + i;
    float4 m0 = *(const float4*)&wsM[mo];
    float4 m1 = *(const float4*)&wsM[mh + mo];
    float4 m2 = *(const float4*)&wsM[2 * mh + mo];
    float4 l0 = *(const float4*)&wsL[mo];
    float4 l1 = *(const float4*)&wsL[mh + mo];
    float4 l2 = *(const float4*)&wsL[2 * mh + mo];
    uint2 o0u = *(const uint2*)&wsO[idx];
    uint2 o1u = *(const uint2*)&wsO[oh + idx];
    uint2 o2u = *(const uint2*)&wsO[2 * oh + idx];
    const short* o0s = (const short*)&o0u;
    const short* o1s = (const short*)&o1u;
    const short* o2s = (const short*)&o2u;
    const float* m0p = (const float*)&m0; const float* m1p = (const float*)&m1;
    const float* m2p = (const float*)&m2;
    const float* l0p = (const float*)&l0; const float* l1p = (const float*)&l1;
    const float* l2p = (const float*)&l2;
    float4 res;
    float* rp = (float*)&res;
    #pragma unroll
    for (int j = 0; j < 4; j++) {
        float m = fmaxf(fmaxf(m0p[j], m1p[j]), m2p[j]);
        float a0 = exp2f(m0p[j] - m);
        float a1 = exp2f(m1p[j] - m);
        float a2 = exp2f(m2p[j] - m);
        rp[j] = (a0 * h2f(o0s[j]) + a1 * h2f(o1s[j]) + a2 * h2f(o2s[j])) /
                (a0 * l0p[j] + a1 * l1p[j] + a2 * l2p[j]);
    }
    *(float4*)&out[idx] = res;
}

// ---------------------------------------------------------------------------
extern "C" void kernel_launch(void* const* d_in, const int* in_sizes, int n_in,
                              void* d_out, int out_size, void* d_ws, size_t ws_size,
                              hipStream_t stream) {
    const float* x     = (const float*)d_in[0];
    const float* wq    = (const float*)d_in[1];
    const float* bq    = (const float*)d_in[2];
    const float* wk    = (const float*)d_in[3];
    const float* bk    = (const float*)d_in[4];
    const float* wv    = (const float*)d_in[5];
    const float* bv    = (const float*)d_in[6];
    const float* rel_d = (const float*)d_in[7];
    const float* rel_h = (const float*)d_in[8];
    const float* rel_w = (const float*)d_in[9];
    float* out = (float*)d_out;

    size_t vsz  = (size_t)B_ * HEADS * DK * NVOX;        // 1,769,472
    size_t psz  = (size_t)HEADS * NVOX * DK;             // 442,368
    short* Qf   = (short*)d_ws;                          // 32-wide
    short* Kf   = Qf + vsz;
    short* Vf   = Kf + vsz;
    short* posf = Vf + vsz;                              // per-h pos
    short* wf   = posf + psz;                            // 196,608 shorts
    short* wsO  = wf + (size_t)3 * C_ * C_;              // 3*vsz shorts (f16)
    float* wsM  = (float*)(wsO + 3 * vsz);               // 3*B*H*NVOX floats
    float* wsL  = wsM + 3 * (size_t)B_ * HEADS * NVOX;
    short* xf   = wsO;                                   // aliases wsO (dead before attn)

    prep_kernel<<<dim3(840), dim3(256), 0, stream>>>(
        x, wq, wk, wv, rel_d, rel_h, rel_w, wf, xf, posf);
    fproj_kernel<<<dim3(NVOX / 64, HEADS, B_), dim3(384), 0, stream>>>(
        xf, wf, bq, bk, bv, Qf, Kf, Vf);
    attn_kernel<<<dim3(ITILES * JSPLIT * HEADS * B_), dim3(256), 0, stream>>>(
        Qf, Kf, Vf, posf, wsO, wsM, wsL);
    combine_kernel<<<dim3((int)(vsz / 1024)), dim3(256), 0, stream>>>(wsO, wsM, wsL, out);
}